// Round 10
// baseline (401.157 us; speedup 1.0000x reference)
//
#include <hip/hip_runtime.h>
#include <math.h>

#define N_TOKENS 16384
#define D_MODEL 2048
#define NUM_EXPERTS 64
#define TOPK 8
#define BLOCK_THREADS 512       // 8 waves: 2 k-halves x 2 roles x 2 token-groups
#define T_PER_GROUP 8
#define TOK_PER_BLOCK 16

typedef float f32x8 __attribute__((ext_vector_type(8)));

__device__ __forceinline__ float f4c(const float4& v, int j) {
    return j == 0 ? v.x : j == 1 ? v.y : j == 2 ? v.z : v.w;
}

// Pre-pass: WT4[kk][col] (col = role*64 + e) = {W_role[4kk+j][e], j=0..3}
__global__ __launch_bounds__(256)
void wt_build_kernel(const float* __restrict__ Wg, const float* __restrict__ Wn,
                     float4* __restrict__ WT4) {
    const int id  = blockIdx.x * 256 + threadIdx.x;    // 0..65535
    const int kk  = id >> 7;
    const int col = id & 127;
    const int ro  = col >> 6;
    const int e   = col & 63;
    const float* src = (ro ? Wn : Wg) + (size_t)(kk * 4) * NUM_EXPERTS + e;
    WT4[id] = make_float4(src[0], src[NUM_EXPERTS], src[2 * NUM_EXPERTS], src[3 * NUM_EXPERTS]);
}

__global__ __launch_bounds__(BLOCK_THREADS, 6)
void noisy_topk_router_kernel(const float* __restrict__ x,
                              const float* __restrict__ eps,
                              const float4* __restrict__ WT4,
                              const float* __restrict__ bg,
                              const float* __restrict__ bn,
                              float* __restrict__ out_probs,
                              float* __restrict__ out_idx)
{
    // fp64 partials: [khalf][role][token][expert] = 32 KB
    __shared__ double exbuf[2][2][TOK_PER_BLOCK][NUM_EXPERTS];

    const int tid  = threadIdx.x;
    const int lane = tid & 63;
    const int w    = __builtin_amdgcn_readfirstlane(tid >> 6);
    const int kh   = w & 1;           // k-half: 0 -> k<1024, 1 -> k>=1024
    const int ro   = (w >> 1) & 1;    // 0 = gate, 1 = noise
    const int gi   = w >> 2;          // token group 0..1
    const int btok0 = blockIdx.x * TOK_PER_BLOCK;
    const int tok0  = btok0 + gi * T_PER_GROUP;

    // scalar base for x: token tok0, this wave's k-half. Per-token offset is a
    // compile-time imm (t * 8192 B); running k-offset goes in an SGPR.
    const float* xbase = x + (size_t)tok0 * D_MODEL + kh * (D_MODEL / 2);

    // W stream for this wave's (k-half, role): float4 per 4 k's, coalesced
    const float4* wtp = WT4 + (size_t)kh * (D_MODEL / 2 / 4) * 128 + ro * 64 + lane;

    float  ag[T_PER_GROUP];
    double dd[T_PER_GROUP];
    #pragma unroll
    for (int t = 0; t < T_PER_GROUP; ++t) { ag[t] = 0.f; dd[t] = 0.0; }

    // 32 periods of 32 k each (8 float4 W-steps). Per period: 8 W loads
    // (register ring, deep in flight), 4x {scalar x batch + 64 FMA},
    // fp32->fp64 fold. Convoy barrier every 2 periods (64 k).
    #pragma unroll 1
    for (int p = 0; p < 32; ++p) {
        const float4* wp = wtp + (size_t)p * 8 * 128;
        float4 wv[8];
        #pragma unroll
        for (int s = 0; s < 8; ++s) wv[s] = wp[(size_t)s * 128];   // 8 in flight

        #pragma unroll
        for (int q = 0; q < 4; ++q) {   // 8 k's per q
            const unsigned soff = (unsigned)(p * 128 + q * 32);    // bytes
            f32x8 xs[T_PER_GROUP];
            // NOTE: "=&s" early-clobber is REQUIRED — SMEM results return
            // asynchronously between issues; without it LLVM may alias an
            // output tuple with [b]/[o] and a returning load corrupts the
            // base address for the later loads (round-9 crash).
            asm volatile(
                "s_load_dwordx8 %0, %[b], %[o]\n\t"
                "s_load_dwordx8 %1, %[b], %[o] offset:8192\n\t"
                "s_load_dwordx8 %2, %[b], %[o] offset:16384\n\t"
                "s_load_dwordx8 %3, %[b], %[o] offset:24576\n\t"
                "s_load_dwordx8 %4, %[b], %[o] offset:32768\n\t"
                "s_load_dwordx8 %5, %[b], %[o] offset:40960\n\t"
                "s_load_dwordx8 %6, %[b], %[o] offset:49152\n\t"
                "s_load_dwordx8 %7, %[b], %[o] offset:57344\n\t"
                "s_waitcnt lgkmcnt(0)"
                : "=&s"(xs[0]), "=&s"(xs[1]), "=&s"(xs[2]), "=&s"(xs[3]),
                  "=&s"(xs[4]), "=&s"(xs[5]), "=&s"(xs[6]), "=&s"(xs[7])
                : [b] "s"(xbase), [o] "s"(soff));

            #pragma unroll
            for (int st = 0; st < 2; ++st) {        // two float4 W-steps per q
                const float4 wvv = wv[2 * q + st];
                #pragma unroll
                for (int j = 0; j < 4; ++j) {
                    const float wj = f4c(wvv, j);
                    #pragma unroll
                    for (int t = 0; t < T_PER_GROUP; ++t)
                        ag[t] = fmaf(xs[t][st * 4 + j], wj, ag[t]);
                }
            }
        }
        #pragma unroll
        for (int t = 0; t < T_PER_GROUP; ++t) { dd[t] += (double)ag[t]; ag[t] = 0.f; }
        if (p & 1) __builtin_amdgcn_s_barrier();   // convoy only
    }

    // deposit fp64 partials
    #pragma unroll
    for (int t = 0; t < T_PER_GROUP; ++t)
        exbuf[kh][ro][gi * T_PER_GROUP + t][lane] = dd[t];
    __syncthreads();

    // epilogue: each wave finishes 2 tokens (softplus + noise + top-8 + softmax)
    const float bgv = bg[lane];
    const float bnv = bn[lane];

    #pragma unroll 1
    for (int q = 0; q < 2; ++q) {
        const int tt  = w * 2 + q;
        const int tok = btok0 + tt;
        const double logit = (exbuf[0][0][tt][lane] + exbuf[1][0][tt][lane]) + (double)bgv;
        const double nvv   = (exbuf[0][1][tt][lane] + exbuf[1][1][tt][lane]) + (double)bnv;
        const double sp    = (nvv > 0.0) ? (nvv + log1p(exp(-nvv))) : log1p(exp(nvv));
        const double noisy = logit + (double)eps[(size_t)tok * NUM_EXPERTS + lane] * sp;

        // iterative top-8; tie-break: higher value, then lower index (lax.top_k)
        double cur = noisy;
        double m = 0.0, sum = 0.0;
        int    sel = 0;
        float  my_idx = 0.0f;
        #pragma unroll
        for (int rk = 0; rk < TOPK; ++rk) {
            double bv = cur;
            int    bi = lane;
            #pragma unroll
            for (int off = 32; off >= 1; off >>= 1) {
                double ov = __shfl_xor(bv, off);
                int    oi = __shfl_xor(bi, off);
                if (ov > bv || (ov == bv && oi < bi)) { bv = ov; bi = oi; }
            }
            if (rk == 0) m = bv;
            sum += exp(bv - m);
            if (lane == bi) { sel = 1; cur = -INFINITY; }
            if (lane == rk) my_idx = (float)bi;
        }

        out_probs[(size_t)tok * NUM_EXPERTS + lane] = (float)(sel ? exp(noisy - m) / sum : 0.0);
        if (lane < TOPK) out_idx[(size_t)tok * TOPK + lane] = my_idx;
    }
}

extern "C" void kernel_launch(void* const* d_in, const int* in_sizes, int n_in,
                              void* d_out, int out_size, void* d_ws, size_t ws_size,
                              hipStream_t stream) {
    const float* x   = (const float*)d_in[0];
    const float* eps = (const float*)d_in[1];
    const float* Wg  = (const float*)d_in[2];
    const float* bg  = (const float*)d_in[3];
    const float* Wn  = (const float*)d_in[4];
    const float* bn  = (const float*)d_in[5];

    float* out_probs = (float*)d_out;                                  // [N, E]
    float* out_idx   = (float*)d_out + (size_t)N_TOKENS * NUM_EXPERTS; // [N, K]

    float4* WT4 = (float4*)d_ws;    // 512 * 128 * 16 B = 1 MB

    wt_build_kernel<<<dim3(256), dim3(256), 0, stream>>>(Wg, Wn, WT4);

    dim3 grid(N_TOKENS / TOK_PER_BLOCK);   // 1024
    dim3 block(BLOCK_THREADS);             // 512
    noisy_topk_router_kernel<<<grid, block, 0, stream>>>(
        x, eps, WT4, bg, bn, out_probs, out_idx);
}

// Round 11
// 255.727 us; speedup vs baseline: 1.5687x; 1.5687x over previous
//
#include <hip/hip_runtime.h>
#include <math.h>

#define N_TOKENS 16384
#define D_MODEL 2048
#define NUM_EXPERTS 64
#define TOPK 8
#define BLOCK_THREADS 512       // 8 waves: 2 k-halves x 2 roles x 2 token-groups
#define T_PER_GROUP 8
#define TOK_PER_BLOCK 16
#define KHALF4 (D_MODEL / 2 / 4)    // 256 float4 steps per wave

__device__ __forceinline__ float f4c(const float4& v, int j) {
    return j == 0 ? v.x : j == 1 ? v.y : j == 2 ? v.z : v.w;
}

// Pre-pass: WT4[kk][col] (col = role*64 + e) = {W_role[4kk+j][e], j=0..3}
__global__ __launch_bounds__(256)
void wt_build_kernel(const float* __restrict__ Wg, const float* __restrict__ Wn,
                     float4* __restrict__ WT4) {
    const int id  = blockIdx.x * 256 + threadIdx.x;    // 0..65535
    const int kk  = id >> 7;
    const int col = id & 127;
    const int ro  = col >> 6;
    const int e   = col & 63;
    const float* src = (ro ? Wn : Wg) + (size_t)(kk * 4) * NUM_EXPERTS + e;
    WT4[id] = make_float4(src[0], src[NUM_EXPERTS], src[2 * NUM_EXPERTS], src[3 * NUM_EXPERTS]);
}

__global__ __launch_bounds__(BLOCK_THREADS, 8)
void noisy_topk_router_kernel(const float* __restrict__ x,
                              const float* __restrict__ eps,
                              const float4* __restrict__ WT4,
                              const float* __restrict__ bg,
                              const float* __restrict__ bn,
                              float* __restrict__ out_probs,
                              float* __restrict__ out_idx)
{
    // fp64 partial accumulators live in LDS (not VGPRs — round 8 spilled them):
    // [khalf][role][token][expert] = 32 KB
    __shared__ double exbuf[2][2][TOK_PER_BLOCK][NUM_EXPERTS];

    const int tid  = threadIdx.x;
    const int lane = tid & 63;
    const int w    = __builtin_amdgcn_readfirstlane(tid >> 6);
    const int kh   = w & 1;           // k-half: 0 -> k<1024, 1 -> k>=1024
    const int ro   = (w >> 1) & 1;    // 0 = gate, 1 = noise
    const int gi   = w >> 2;          // token group 0..1
    const int btok0 = blockIdx.x * TOK_PER_BLOCK;
    const int tok0  = btok0 + gi * T_PER_GROUP;

    // zero the fp64 accumulators (4096 doubles / 512 threads = 8 each)
    {
        double* z = &exbuf[0][0][0][0];
        #pragma unroll
        for (int i = 0; i < 8; ++i) z[tid + i * BLOCK_THREADS] = 0.0;
    }
    __syncthreads();

    // x pointers, offset to this wave's k-half (addresses are wave-uniform)
    const float4* xb[T_PER_GROUP];
    #pragma unroll
    for (int t = 0; t < T_PER_GROUP; ++t)
        xb[t] = reinterpret_cast<const float4*>(x + (size_t)(tok0 + t) * D_MODEL)
                + kh * KHALF4;

    // W stream for this wave's (k-half, role): one float4 per 4 k's, coalesced
    const float4* wtp = WT4 + (size_t)kh * KHALF4 * 128 + ro * 64 + lane;

    // fp64 fold target: &exbuf[kh][ro][gi*8 + t][lane] = accb[t*64].
    // volatile so the compiler cannot promote the RMW back into registers
    // (that promotion IS the round-8 spill).
    volatile double* accb = &exbuf[kh][ro][gi * T_PER_GROUP][0] + lane;

    float ag[T_PER_GROUP];
    #pragma unroll
    for (int t = 0; t < T_PER_GROUP; ++t) ag[t] = 0.f;

    // 32 periods of 32 k (8 float4-steps). fp32 accumulate within a period,
    // fp64 LDS fold per period (same add order as rounds 2-8), convoy barrier
    // every 2 periods.
    #pragma unroll 1
    for (int p = 0; p < 32; ++p) {
        #pragma unroll
        for (int s = 0; s < 8; ++s) {
            const int i = p * 8 + s;
            const float4 wt = wtp[(size_t)i * 128];
            float4 xv[T_PER_GROUP];
            #pragma unroll
            for (int t = 0; t < T_PER_GROUP; ++t) xv[t] = xb[t][i];  // uniform addr, broadcast
            #pragma unroll
            for (int j = 0; j < 4; ++j) {
                const float wj = f4c(wt, j);
                #pragma unroll
                for (int t = 0; t < T_PER_GROUP; ++t)
                    ag[t] = fmaf(f4c(xv[t], j), wj, ag[t]);
            }
        }
        #pragma unroll
        for (int t = 0; t < T_PER_GROUP; ++t) {
            accb[t * NUM_EXPERTS] = accb[t * NUM_EXPERTS] + (double)ag[t];
            ag[t] = 0.f;
        }
        if (p & 1) __builtin_amdgcn_s_barrier();   // convoy only
    }

    __syncthreads();   // all folds visible before cross-wave epilogue reads

    // epilogue: each wave finishes 2 tokens (softplus + noise + top-8 + softmax)
    const float bgv = bg[lane];
    const float bnv = bn[lane];

    #pragma unroll 1
    for (int q = 0; q < 2; ++q) {
        const int tt  = w * 2 + q;
        const int tok = btok0 + tt;
        const double logit = (exbuf[0][0][tt][lane] + exbuf[1][0][tt][lane]) + (double)bgv;
        const double nvv   = (exbuf[0][1][tt][lane] + exbuf[1][1][tt][lane]) + (double)bnv;
        const double sp    = (nvv > 0.0) ? (nvv + log1p(exp(-nvv))) : log1p(exp(nvv));
        const double noisy = logit + (double)eps[(size_t)tok * NUM_EXPERTS + lane] * sp;

        // iterative top-8; tie-break: higher value, then lower index (lax.top_k)
        double cur = noisy;
        double m = 0.0, sum = 0.0;
        int    sel = 0;
        float  my_idx = 0.0f;
        #pragma unroll
        for (int rk = 0; rk < TOPK; ++rk) {
            double bv = cur;
            int    bi = lane;
            #pragma unroll
            for (int off = 32; off >= 1; off >>= 1) {
                double ov = __shfl_xor(bv, off);
                int    oi = __shfl_xor(bi, off);
                if (ov > bv || (ov == bv && oi < bi)) { bv = ov; bi = oi; }
            }
            if (rk == 0) m = bv;
            sum += exp(bv - m);
            if (lane == bi) { sel = 1; cur = -INFINITY; }
            if (lane == rk) my_idx = (float)bi;
        }

        out_probs[(size_t)tok * NUM_EXPERTS + lane] = (float)(sel ? exp(noisy - m) / sum : 0.0);
        if (lane < TOPK) out_idx[(size_t)tok * TOPK + lane] = my_idx;
    }
}

extern "C" void kernel_launch(void* const* d_in, const int* in_sizes, int n_in,
                              void* d_out, int out_size, void* d_ws, size_t ws_size,
                              hipStream_t stream) {
    const float* x   = (const float*)d_in[0];
    const float* eps = (const float*)d_in[1];
    const float* Wg  = (const float*)d_in[2];
    const float* bg  = (const float*)d_in[3];
    const float* Wn  = (const float*)d_in[4];
    const float* bn  = (const float*)d_in[5];

    float* out_probs = (float*)d_out;                                  // [N, E]
    float* out_idx   = (float*)d_out + (size_t)N_TOKENS * NUM_EXPERTS; // [N, K]

    float4* WT4 = (float4*)d_ws;    // 512 * 128 * 16 B = 1 MB

    wt_build_kernel<<<dim3(256), dim3(256), 0, stream>>>(Wg, Wn, WT4);

    dim3 grid(N_TOKENS / TOK_PER_BLOCK);   // 1024
    dim3 block(BLOCK_THREADS);             // 512
    noisy_topk_router_kernel<<<grid, block, 0, stream>>>(
        x, eps, WT4, bg, bn, out_probs, out_idx);
}

// Round 12
// 161.765 us; speedup vs baseline: 2.4799x; 1.5809x over previous
//
#include <hip/hip_runtime.h>
#include <math.h>

#define N_TOKENS 16384
#define D_MODEL  2048
#define NE       64
#define TOPK     8

typedef float f32x4 __attribute__((ext_vector_type(4)));
typedef short s16x8 __attribute__((ext_vector_type(8)));
typedef short s16x4 __attribute__((ext_vector_type(4)));

#define LDSROW 40                      // shorts per x-row incl pad (80 B)
#define XS_BUF (3 * 64 * LDSROW)       // shorts per double-buffer half
#define ACC_LD 129                     // fp64 acc row stride (conflict-free dump)

// RNE float->bf16, returns the rounded-back float and the bf16 bits.
__device__ __forceinline__ float bf16_rne(float v, short* s) {
    unsigned u = __float_as_uint(v);
    unsigned r = (u + 0x7fffu + ((u >> 16) & 1u)) & 0xffff0000u;
    *s = (short)(r >> 16);
    return __uint_as_float(r);
}

// Pre-pass: B-fragments for [Wg | Wn] (N=128), 3 splits, in exact lane order:
// BF[((c*8+ct)*3+s)*64 + l][e] = split_s(W'[c*32 + (l>>4)*8 + e][ct*16 + (l&15)])
__global__ __launch_bounds__(256)
void bf_build(const float* __restrict__ Wg, const float* __restrict__ Wn,
              s16x8* __restrict__ BF) {
    const int id  = blockIdx.x * 256 + threadIdx.x;   // 0..98303
    const int l   = id & 63;
    const int s   = (id >> 6) % 3;
    const int ctc = (id >> 6) / 3;        // c*8 + ct
    const int ct  = ctc & 7;
    const int c   = ctc >> 3;
    const int k0  = c * 32 + (l >> 4) * 8;
    const int col = ct * 16 + (l & 15);
    const float* W = (col < NE) ? (Wg + col) : (Wn + (col - NE));
    s16x8 o;
    #pragma unroll
    for (int e = 0; e < 8; ++e) {
        float v  = W[(size_t)(k0 + e) * NE];
        short h, m, lo;
        float hf = bf16_rne(v, &h);
        float r1 = v - hf;                 // exact
        float mf = bf16_rne(r1, &m);
        float r2 = r1 - mf;                // exact
        bf16_rne(r2, &lo);
        o[e] = (s == 0) ? h : (s == 1) ? m : lo;
    }
    BF[id] = o;
}

__global__ __launch_bounds__(512, 2)
void router_mfma(const float* __restrict__ x, const float* __restrict__ eps,
                 const s16x8* __restrict__ BF, const float* __restrict__ bg,
                 const float* __restrict__ bn, float* __restrict__ out_probs,
                 float* __restrict__ out_idx)
{
    __shared__ char smem[64 * ACC_LD * 8];   // 66048 B; xsplit (30720 B) aliased first
    short*  xsp = (short*)smem;
    double* acc = (double*)smem;

    const int tid  = threadIdx.x;
    const int lane = tid & 63;
    const int wv   = tid >> 6;            // 8 waves
    const int tile = wv >> 1;             // M-tile 0..3 (16 rows each)
    const int ch   = wv & 1;              // N-half: ctiles ch*4 .. ch*4+3
    const int row0 = blockIdx.x * 64;

    // ---- convert-role mapping: thread -> (row, float4-slot) ----
    const int crow = tid >> 3;            // 0..63
    const int ckq  = tid & 7;             // 0..7
    const float4* xcp = (const float4*)(x + (size_t)(row0 + crow) * D_MODEL) + ckq;
    const int cbase = crow * LDSROW + ckq * 4;   // short index within a split plane

    auto convert_store = [&](float4 a, int bb) {
        float vv[4] = {a.x, a.y, a.z, a.w};
        s16x4 H, M, L;
        #pragma unroll
        for (int e = 0; e < 4; ++e) {
            short hh, mm, ll;
            float hf = bf16_rne(vv[e], &hh);
            float r1 = vv[e] - hf;
            float mf = bf16_rne(r1, &mm);
            float r2 = r1 - mf;
            bf16_rne(r2, &ll);
            H[e] = hh; M[e] = mm; L[e] = ll;
        }
        short* xb = xsp + bb * XS_BUF;
        *(s16x4*)&xb[cbase]                = H;
        *(s16x4*)&xb[cbase + 64 * LDSROW]  = M;
        *(s16x4*)&xb[cbase + 128 * LDSROW] = L;
    };

    // ---- wave MFMA state ----
    const int abase = (tile * 16 + (lane & 15)) * LDSROW + (lane >> 4) * 8;
    const s16x8* bfp = BF + lane;

    f32x4  C[4];
    double facc[4][4];
    #pragma unroll
    for (int i = 0; i < 4; ++i) {
        C[i] = (f32x4){0.f, 0.f, 0.f, 0.f};
        #pragma unroll
        for (int j = 0; j < 4; ++j) facc[i][j] = 0.0;
    }

    auto do_chunk = [&](int c, int bb) {
        s16x8 Bv[4][3];
        #pragma unroll
        for (int i = 0; i < 4; ++i)
            #pragma unroll
            for (int s = 0; s < 3; ++s)
                Bv[i][s] = bfp[(size_t)(((c * 8) + ch * 4 + i) * 3 + s) * 64];
        const short* xb = xsp + bb * XS_BUF;
        s16x8 Ah = *(const s16x8*)&xb[abase];
        s16x8 Am = *(const s16x8*)&xb[abase + 64 * LDSROW];
        s16x8 Al = *(const s16x8*)&xb[abase + 128 * LDSROW];
        #pragma unroll
        for (int i = 0; i < 4; ++i) {   // ascending magnitude within chunk
            C[i] = __builtin_amdgcn_mfma_f32_16x16x32_bf16(Am, Bv[i][1], C[i], 0, 0, 0); // mm
            C[i] = __builtin_amdgcn_mfma_f32_16x16x32_bf16(Ah, Bv[i][2], C[i], 0, 0, 0); // hl
            C[i] = __builtin_amdgcn_mfma_f32_16x16x32_bf16(Al, Bv[i][0], C[i], 0, 0, 0); // lh
            C[i] = __builtin_amdgcn_mfma_f32_16x16x32_bf16(Ah, Bv[i][1], C[i], 0, 0, 0); // hm
            C[i] = __builtin_amdgcn_mfma_f32_16x16x32_bf16(Am, Bv[i][0], C[i], 0, 0, 0); // mh
            C[i] = __builtin_amdgcn_mfma_f32_16x16x32_bf16(Ah, Bv[i][0], C[i], 0, 0, 0); // hh
        }
    };

    #define CONVOY_BARRIER() do {                                   \
        asm volatile("s_waitcnt lgkmcnt(0)" ::: "memory");          \
        __builtin_amdgcn_s_barrier();                               \
        __builtin_amdgcn_sched_barrier(0);                          \
    } while (0)

    // ---- prologue: chunk 0 -> buf0; prefetch chunk 1 ----
    convert_store(xcp[0], 0);
    float4 xa, xb4;
    xb4 = xcp[8];                          // chunk 1
    CONVOY_BARRIER();

    // ---- main loop, 2 chunks per iteration ----
    #pragma unroll 1
    for (int c = 0; c < 64; c += 2) {
        // even body: MFMA chunk c (buf0); convert chunk c+1 -> buf1; prefetch c+2
        if (c + 2 < 64) xa = xcp[(c + 2) * 8];
        convert_store(xb4, 1);
        do_chunk(c, 0);
        CONVOY_BARRIER();

        // odd body: MFMA chunk c+1 (buf1); convert chunk c+2 -> buf0; prefetch c+3
        if (c + 3 < 64) xb4 = xcp[(c + 3) * 8];
        if (c + 2 < 64) convert_store(xa, 0);
        do_chunk(c + 1, 1);
        #pragma unroll
        for (int i = 0; i < 4; ++i)
            #pragma unroll
            for (int j = 0; j < 4; ++j) { facc[i][j] += (double)C[i][j]; C[i][j] = 0.f; }
        CONVOY_BARRIER();
    }

    __syncthreads();   // all LDS reads done before acc overwrites xsplit

    // ---- dump fp64 accs: row = tile*16 + (lane>>4)*4 + j, col = ch*64 + i*16 + (lane&15)
    #pragma unroll
    for (int i = 0; i < 4; ++i)
        #pragma unroll
        for (int j = 0; j < 4; ++j)
            acc[(size_t)(tile * 16 + (lane >> 4) * 4 + j) * ACC_LD
                + ch * 64 + i * 16 + (lane & 15)] = facc[i][j];
    __syncthreads();

    // ---- epilogue (identical numerics to rounds 2-11): 8 tokens per wave ----
    const float bgv = bg[lane];
    const float bnv = bn[lane];

    #pragma unroll 1
    for (int q = 0; q < 8; ++q) {
        const int tt  = wv * 8 + q;
        const int tok = row0 + tt;
        const double logit = acc[(size_t)tt * ACC_LD + lane] + (double)bgv;
        const double nvv   = acc[(size_t)tt * ACC_LD + 64 + lane] + (double)bnv;
        const double sp    = (nvv > 0.0) ? (nvv + log1p(exp(-nvv))) : log1p(exp(nvv));
        const double noisy = logit + (double)eps[(size_t)tok * NE + lane] * sp;

        // iterative top-8; tie-break: higher value, then lower index (lax.top_k)
        double cur = noisy;
        double m = 0.0, sum = 0.0;
        int    sel = 0;
        float  my_idx = 0.0f;
        #pragma unroll
        for (int rk = 0; rk < TOPK; ++rk) {
            double bv = cur;
            int    bi = lane;
            #pragma unroll
            for (int off = 32; off >= 1; off >>= 1) {
                double ov = __shfl_xor(bv, off);
                int    oi = __shfl_xor(bi, off);
                if (ov > bv || (ov == bv && oi < bi)) { bv = ov; bi = oi; }
            }
            if (rk == 0) m = bv;
            sum += exp(bv - m);
            if (lane == bi) { sel = 1; cur = -INFINITY; }
            if (lane == rk) my_idx = (float)bi;
        }

        out_probs[(size_t)tok * NE + lane] = (float)(sel ? exp(noisy - m) / sum : 0.0);
        if (lane < TOPK) out_idx[(size_t)tok * TOPK + lane] = my_idx;
    }
}

extern "C" void kernel_launch(void* const* d_in, const int* in_sizes, int n_in,
                              void* d_out, int out_size, void* d_ws, size_t ws_size,
                              hipStream_t stream) {
    const float* x   = (const float*)d_in[0];
    const float* eps = (const float*)d_in[1];
    const float* Wg  = (const float*)d_in[2];
    const float* bg  = (const float*)d_in[3];
    const float* Wn  = (const float*)d_in[4];
    const float* bn  = (const float*)d_in[5];

    float* out_probs = (float*)d_out;                              // [N, E]
    float* out_idx   = (float*)d_out + (size_t)N_TOKENS * NE;      // [N, K]

    s16x8* BF = (s16x8*)d_ws;    // 98304 * 16 B = 1.5 MB of B-fragments

    bf_build<<<dim3(384), dim3(256), 0, stream>>>(Wg, Wn, BF);

    router_mfma<<<dim3(N_TOKENS / 64), dim3(512), 0, stream>>>(
        x, eps, BF, bg, bn, out_probs, out_idx);
}

// Round 13
// 128.959 us; speedup vs baseline: 3.1107x; 1.2544x over previous
//
#include <hip/hip_runtime.h>
#include <math.h>

#define N_TOKENS 16384
#define D_MODEL  2048
#define NE       64
#define TOPK     8

typedef float f32x4 __attribute__((ext_vector_type(4)));
typedef short s16x8 __attribute__((ext_vector_type(8)));

#define LDSROW 40                     // shorts per x-row (32 data + 8 pad)
#define PLANE  (16 * LDSROW)          // 640 shorts per split plane
#define XS_BUF (3 * PLANE)            // 1920 shorts per double-buffer half
#define ACC_LD 129                    // fp64 acc row stride

// RNE float->bf16, returns the rounded-back float and the bf16 bits.
__device__ __forceinline__ float bf16_rne(float v, short* s) {
    unsigned u = __float_as_uint(v);
    unsigned r = (u + 0x7fffu + ((u >> 16) & 1u)) & 0xffff0000u;
    *s = (short)(r >> 16);
    return __uint_as_float(r);
}

// Pre-pass (unchanged from R12): B-fragments for [Wg | Wn] (N=128), 3 splits:
// BF[((c*8+ct)*3+s)*64 + l][e] = split_s(W'[c*32 + (l>>4)*8 + e][ct*16 + (l&15)])
__global__ __launch_bounds__(256)
void bf_build(const float* __restrict__ Wg, const float* __restrict__ Wn,
              s16x8* __restrict__ BF) {
    const int id  = blockIdx.x * 256 + threadIdx.x;   // 0..98303
    const int l   = id & 63;
    const int s   = (id >> 6) % 3;
    const int ctc = (id >> 6) / 3;        // c*8 + ct
    const int ct  = ctc & 7;
    const int c   = ctc >> 3;
    const int k0  = c * 32 + (l >> 4) * 8;
    const int col = ct * 16 + (l & 15);
    const float* W = (col < NE) ? (Wg + col) : (Wn + (col - NE));
    s16x8 o;
    #pragma unroll
    for (int e = 0; e < 8; ++e) {
        float v  = W[(size_t)(k0 + e) * NE];
        short h, m, lo;
        float hf = bf16_rne(v, &h);
        float r1 = v - hf;                 // exact
        float mf = bf16_rne(r1, &m);
        float r2 = r1 - mf;                // exact
        bf16_rne(r2, &lo);
        o[e] = (s == 0) ? h : (s == 1) ? m : lo;
    }
    BF[id] = o;
}

__global__ __launch_bounds__(512, 8)
void router_mfma(const float* __restrict__ x, const float* __restrict__ eps,
                 const s16x8* __restrict__ BF, const float* __restrict__ bg,
                 const float* __restrict__ bn, float* __restrict__ out_probs,
                 float* __restrict__ out_idx)
{
    __shared__ char smem[16 * ACC_LD * 8];   // 16512 B; xsplit (7680 B) aliased
    short*  xsp = (short*)smem;
    double* acc = (double*)smem;

    const int tid  = threadIdx.x;
    const int lane = tid & 63;
    const int wv   = tid >> 6;            // wave id = ctile 0..7 (16 cols each)
    const int row0 = blockIdx.x * 16;

    // ---- convert mapping: one float per thread per 32-k chunk ----
    const int crow = tid >> 5;            // 0..15
    const int ck   = tid & 31;            // 0..31
    const float* xp = x + (size_t)(row0 + crow) * D_MODEL + ck;
    const int cbase = crow * LDSROW + ck;

    auto convert_store = [&](float v, int bb) {
        short h, m, l;
        float hf = bf16_rne(v, &h);
        float r1 = v - hf;                 // exact
        float mf = bf16_rne(r1, &m);
        bf16_rne(r1 - mf, &l);
        short* xb = xsp + bb * XS_BUF;
        xb[cbase]             = h;
        xb[cbase + PLANE]     = m;
        xb[cbase + 2 * PLANE] = l;
    };

    // ---- wave MFMA state ----
    const int abase = (lane & 15) * LDSROW + (lane >> 4) * 8;
    const s16x8* bfp = BF + lane;

    f32x4  C = {0.f, 0.f, 0.f, 0.f};
    double facc[4] = {0.0, 0.0, 0.0, 0.0};

    auto do_chunk = [&](int c, int bb) {
        s16x8 Bv[3];
        #pragma unroll
        for (int s = 0; s < 3; ++s)
            Bv[s] = bfp[(size_t)(((c * 8) + wv) * 3 + s) * 64];
        const short* xb = xsp + bb * XS_BUF;
        s16x8 Ah = *(const s16x8*)&xb[abase];
        s16x8 Am = *(const s16x8*)&xb[abase + PLANE];
        s16x8 Al = *(const s16x8*)&xb[abase + 2 * PLANE];
        // same term order as R12 (ascending magnitude) -> identical numerics
        C = __builtin_amdgcn_mfma_f32_16x16x32_bf16(Am, Bv[1], C, 0, 0, 0); // mm
        C = __builtin_amdgcn_mfma_f32_16x16x32_bf16(Ah, Bv[2], C, 0, 0, 0); // hl
        C = __builtin_amdgcn_mfma_f32_16x16x32_bf16(Al, Bv[0], C, 0, 0, 0); // lh
        C = __builtin_amdgcn_mfma_f32_16x16x32_bf16(Ah, Bv[1], C, 0, 0, 0); // hm
        C = __builtin_amdgcn_mfma_f32_16x16x32_bf16(Am, Bv[0], C, 0, 0, 0); // mh
        C = __builtin_amdgcn_mfma_f32_16x16x32_bf16(Ah, Bv[0], C, 0, 0, 0); // hh
    };

    #define CONVOY_BARRIER() do {                                   \
        asm volatile("s_waitcnt lgkmcnt(0)" ::: "memory");          \
        __builtin_amdgcn_s_barrier();                               \
        __builtin_amdgcn_sched_barrier(0);                          \
    } while (0)

    // ---- prologue: chunk 0 -> buf0; prefetch chunk 1 ----
    convert_store(xp[0], 0);
    float xa, xb4;
    xb4 = xp[32];                          // chunk 1
    CONVOY_BARRIER();

    // ---- main loop, 2 chunks per iteration ----
    #pragma unroll 1
    for (int c = 0; c < 64; c += 2) {
        if (c + 2 < 64) xa = xp[(c + 2) * 32];
        convert_store(xb4, 1);
        do_chunk(c, 0);
        CONVOY_BARRIER();

        if (c + 3 < 64) xb4 = xp[(c + 3) * 32];
        if (c + 2 < 64) convert_store(xa, 0);
        do_chunk(c + 1, 1);
        #pragma unroll
        for (int j = 0; j < 4; ++j) { facc[j] += (double)C[j]; C[j] = 0.f; }
        CONVOY_BARRIER();
    }

    __syncthreads();   // all LDS reads done before acc overwrites xsplit

    // ---- dump fp64 accs: row = (lane>>4)*4 + j, col = wv*16 + (lane&15) ----
    #pragma unroll
    for (int j = 0; j < 4; ++j)
        acc[(size_t)((lane >> 4) * 4 + j) * ACC_LD + wv * 16 + (lane & 15)] = facc[j];
    __syncthreads();

    // ---- epilogue (identical numerics to R2-R12): 2 tokens per wave ----
    const float bgv = bg[lane];
    const float bnv = bn[lane];

    #pragma unroll 1
    for (int q = 0; q < 2; ++q) {
        const int tt  = wv * 2 + q;
        const int tok = row0 + tt;
        const double logit = acc[(size_t)tt * ACC_LD + lane] + (double)bgv;
        const double nvv   = acc[(size_t)tt * ACC_LD + 64 + lane] + (double)bnv;
        const double sp    = (nvv > 0.0) ? (nvv + log1p(exp(-nvv))) : log1p(exp(nvv));
        const double noisy = logit + (double)eps[(size_t)tok * NE + lane] * sp;

        // iterative top-8; tie-break: higher value, then lower index (lax.top_k)
        double cur = noisy;
        double m = 0.0, sum = 0.0;
        int    sel = 0;
        float  my_idx = 0.0f;
        #pragma unroll
        for (int rk = 0; rk < TOPK; ++rk) {
            double bv = cur;
            int    bi = lane;
            #pragma unroll
            for (int off = 32; off >= 1; off >>= 1) {
                double ov = __shfl_xor(bv, off);
                int    oi = __shfl_xor(bi, off);
                if (ov > bv || (ov == bv && oi < bi)) { bv = ov; bi = oi; }
            }
            if (rk == 0) m = bv;
            sum += exp(bv - m);
            if (lane == bi) { sel = 1; cur = -INFINITY; }
            if (lane == rk) my_idx = (float)bi;
        }

        out_probs[(size_t)tok * NE + lane] = (float)(sel ? exp(noisy - m) / sum : 0.0);
        if (lane < TOPK) out_idx[(size_t)tok * TOPK + lane] = my_idx;
    }
}

extern "C" void kernel_launch(void* const* d_in, const int* in_sizes, int n_in,
                              void* d_out, int out_size, void* d_ws, size_t ws_size,
                              hipStream_t stream) {
    const float* x   = (const float*)d_in[0];
    const float* eps = (const float*)d_in[1];
    const float* Wg  = (const float*)d_in[2];
    const float* bg  = (const float*)d_in[3];
    const float* Wn  = (const float*)d_in[4];
    const float* bn  = (const float*)d_in[5];

    float* out_probs = (float*)d_out;                              // [N, E]
    float* out_idx   = (float*)d_out + (size_t)N_TOKENS * NE;      // [N, K]

    s16x8* BF = (s16x8*)d_ws;    // 98304 * 16 B = 1.5 MB of B-fragments

    bf_build<<<dim3(384), dim3(256), 0, stream>>>(Wg, Wn, BF);

    router_mfma<<<dim3(N_TOKENS / 16), dim3(512), 0, stream>>>(
        x, eps, BF, bg, bn, out_probs, out_idx);
}